// Round 4
// baseline (415.521 us; speedup 1.0000x reference)
//
#include <hip/hip_runtime.h>

#define N_NODES 16384
#define N_EDGES 32768
#define D 128
#define EDGE_DIM 10
#define KH 32          // edge-hidden dim
#define BM 32          // edges per msg block
#define XST 136        // padded LDS row stride (f16)
#define NBL 64         // nodes per node_update block

typedef _Float16 f16;
typedef _Float16 f16x4 __attribute__((ext_vector_type(4)));
typedef _Float16 f16x8 __attribute__((ext_vector_type(8)));
typedef float f32x4 __attribute__((ext_vector_type(4)));

// ---- CSR build ----
__global__ __launch_bounds__(256) void deg_count_kernel(
    const int* __restrict__ ei, int* __restrict__ deg) {
  int e = blockIdx.x * blockDim.x + threadIdx.x;
  if (e < N_EDGES) atomicAdd(&deg[ei[N_EDGES + e]], 1);
}

__global__ __launch_bounds__(1024) void scan_kernel(
    const int* __restrict__ deg, int* __restrict__ rs, int* __restrict__ fill) {
  __shared__ int part[1024];
  int t = threadIdx.x;
  int base = t * 16;
  int loc[16], s = 0;
#pragma unroll
  for (int j = 0; j < 16; j++) { loc[j] = deg[base + j]; s += loc[j]; }
  part[t] = s;
  __syncthreads();
  for (int off = 1; off < 1024; off <<= 1) {
    int add = (t >= off) ? part[t - off] : 0;
    __syncthreads();
    part[t] += add;
    __syncthreads();
  }
  int run = t ? part[t - 1] : 0;
#pragma unroll
  for (int j = 0; j < 16; j++) {
    rs[base + j] = run; fill[base + j] = run; run += loc[j];
  }
  if (t == 1023) rs[N_NODES] = run;
}

// perm[pos] = original edge id; srcs[pos] = src node of that edge
__global__ __launch_bounds__(256) void scatter_kernel(
    const int* __restrict__ ei, int* __restrict__ fill,
    int* __restrict__ perm, int* __restrict__ srcs) {
  int e = blockIdx.x * blockDim.x + threadIdx.x;
  if (e < N_EDGES) {
    int pos = atomicAdd(&fill[ei[N_EDGES + e]], 1);
    perm[pos] = e;
    srcs[pos] = ei[e];
  }
}

// edge MLP in dst-sorted order: h[p] = relu(ea[perm[p]]@l1w + l1b), f16 [E][32]
// blockIdx.y selects layer (0: w1, 1: w2)
__global__ __launch_bounds__(256) void edge_mlp_kernel(
    const float* __restrict__ ea, const int* __restrict__ perm,
    const float* __restrict__ w1l1, const float* __restrict__ b1l1,
    const float* __restrict__ w2l1, const float* __restrict__ b2l1,
    f16* __restrict__ h1, f16* __restrict__ h2) {
  int p = blockIdx.x * blockDim.x + threadIdx.x;
  const float* l1w = blockIdx.y ? w2l1 : w1l1;
  const float* l1b = blockIdx.y ? b2l1 : b1l1;
  f16* h = blockIdx.y ? h2 : h1;
  int e = perm[p];
  float a[EDGE_DIM];
#pragma unroll
  for (int d = 0; d < EDGE_DIM; d++) a[d] = ea[e * EDGE_DIM + d];
  f16 hv[KH];
#pragma unroll
  for (int k = 0; k < KH; k++) {
    float acc = l1b[k];
#pragma unroll
    for (int d = 0; d < EDGE_DIM; d++) acc += a[d] * l1w[d * KH + k];
    hv[k] = (f16)fmaxf(acc, 0.0f);
  }
  f16x8* dst = (f16x8*)(h + (size_t)p * KH);
#pragma unroll
  for (int c = 0; c < 4; c++) dst[c] = *(f16x8*)&hv[c * 8];
}

// One kernel, 6 pack jobs (blockIdx.y):
// y=0/1: l2w [32][128*128](k,i*128+o) -> Bp [i*128+o][k] f16
// y=2/3: l2b [128*128](i*128+o)       -> Bp_bias [(i>>5)*128+o][i&31] f16
// y=4/5: root [j][o]                  -> Rp [(j>>5)*128+o][j&31] f16
__global__ __launch_bounds__(256) void pack_all_kernel(
    const float* __restrict__ w1l2, const float* __restrict__ w2l2,
    const float* __restrict__ b1l2, const float* __restrict__ b2l2,
    const float* __restrict__ rt1, const float* __restrict__ rt2,
    f16* __restrict__ Bp1, f16* __restrict__ Bp2,
    f16* __restrict__ Rp1, f16* __restrict__ Rp2) {
  int y = blockIdx.y;
  int t = blockIdx.x * 256 + threadIdx.x;   // 0..16383
  if (y < 2) {
    const float* l2w = y ? w2l2 : w1l2;
    f16* Bp = y ? Bp2 : Bp1;
    f16 tmp[KH];
#pragma unroll
    for (int k = 0; k < KH; k++) tmp[k] = (f16)l2w[(size_t)k * (D * D) + t];
    f16x8* dst = (f16x8*)(Bp + (size_t)t * KH);
#pragma unroll
    for (int c = 0; c < 4; c++) dst[c] = *(f16x8*)&tmp[c * 8];
  } else {
    const float* src = (y == 2) ? b1l2 : (y == 3) ? b2l2 : (y == 4) ? rt1 : rt2;
    f16* dst = (y == 2) ? (Bp1 + (size_t)D * D * KH)
             : (y == 3) ? (Bp2 + (size_t)D * D * KH)
             : (y == 4) ? Rp1 : Rp2;
    int i = t >> 7, o = t & 127;
    dst[((size_t)(i >> 5) * D + o) * KH + (i & 31)] = (f16)src[t];
  }
}

// msg GEMM: rows stream to f16 msgbuf in dst-sorted order, no atomics.
// K = 4096 enumerated (i,k): A-frag = hreg * splat(x[i]); l2b folded as 4
// extra K=128 slabs with A = x itself.
__global__ __launch_bounds__(256, 4) void msg_mfma_kernel(
    const float* __restrict__ xin, const f16* __restrict__ hf,
    const f16* __restrict__ Bp, const int* __restrict__ srcs,
    f16* __restrict__ msgf) {
  __shared__ f16 Xs[BM][XST];
  __shared__ f16 Hs[BM][KH];
  int t = threadIdx.x;
  int e0 = blockIdx.x * BM;

  if (t < 128) ((f16x8*)Hs)[t] = ((const f16x8*)(hf + (size_t)e0 * KH))[t];
  {
    int r = t >> 3, q = t & 7;     // 8 threads per edge row
    int s = srcs[e0 + r];
    const float4* src = (const float4*)(xin + (size_t)s * D + q * 16);
    f16* dst = &Xs[r][q * 16];
#pragma unroll
    for (int c = 0; c < 4; c++) {
      float4 v = src[c];
      f16x4 h4 = {(f16)v.x, (f16)v.y, (f16)v.z, (f16)v.w};
      *(f16x4*)(dst + c * 4) = h4;
    }
  }
  __syncthreads();

  int L = t & 63, w = t >> 6;
  int quad = L >> 4, lm = L & 15;
  int n0 = w * 32;

  f16x8 hreg[2];
#pragma unroll
  for (int mt = 0; mt < 2; mt++)
    hreg[mt] = *(const f16x8*)&Hs[mt * 16 + lm][quad * 8];

  const f16* bl = Bp + (size_t)(n0 + lm) * KH + quad * 8;

  f32x4 acc[2][2];
#pragma unroll
  for (int mt = 0; mt < 2; mt++)
#pragma unroll
    for (int nt = 0; nt < 2; nt++)
      acc[mt][nt] = (f32x4){0.f, 0.f, 0.f, 0.f};

  for (int ig = 0; ig < D; ig += 8) {
    f16x8 xv[2];
#pragma unroll
    for (int mt = 0; mt < 2; mt++)
      xv[mt] = *(const f16x8*)&Xs[mt * 16 + lm][ig];
#pragma unroll
    for (int jj = 0; jj < 8; jj++) {
      const f16* bi = bl + (size_t)(ig + jj) * (D * KH);
      f16x8 b0 = *(const f16x8*)bi;
      f16x8 b1 = *(const f16x8*)(bi + 16 * KH);
#pragma unroll
      for (int mt = 0; mt < 2; mt++) {
        f16 xs = xv[mt][jj];
        f16x8 xb = {xs, xs, xs, xs, xs, xs, xs, xs};
        f16x8 a = hreg[mt] * xb;
        acc[mt][0] = __builtin_amdgcn_mfma_f32_16x16x32_f16(a, b0, acc[mt][0], 0, 0, 0);
        acc[mt][1] = __builtin_amdgcn_mfma_f32_16x16x32_f16(a, b1, acc[mt][1], 0, 0, 0);
      }
    }
  }

  // l2b fold: K=128 GEMM with A = x fragments
  {
    const f16* bb = Bp + (size_t)D * D * KH;
#pragma unroll
    for (int ig2 = 0; ig2 < 4; ig2++) {
      const f16* b2l = bb + ((size_t)ig2 * D + n0 + lm) * KH + quad * 8;
      f16x8 b0 = *(const f16x8*)b2l;
      f16x8 b1 = *(const f16x8*)(b2l + 16 * KH);
#pragma unroll
      for (int mt = 0; mt < 2; mt++) {
        f16x8 a = *(const f16x8*)&Xs[mt * 16 + lm][ig2 * 32 + quad * 8];
        acc[mt][0] = __builtin_amdgcn_mfma_f32_16x16x32_f16(a, b0, acc[mt][0], 0, 0, 0);
        acc[mt][1] = __builtin_amdgcn_mfma_f32_16x16x32_f16(a, b1, acc[mt][1], 0, 0, 0);
      }
    }
  }

  // C/D: col = lane&15 (+nt*16), row = quad*4 + reg
#pragma unroll
  for (int mt = 0; mt < 2; mt++)
#pragma unroll
    for (int r = 0; r < 4; r++) {
      f16* mg = msgf + (size_t)(e0 + mt * 16 + quad * 4 + r) * D + n0 + lm;
      mg[0] = (f16)acc[mt][0][r];
      mg[16] = (f16)acc[mt][1][r];
    }
}

// node update: out = (relu?) bias + segmean(msgf) + x@root (f16 MFMA)
__global__ __launch_bounds__(256) void node_update_kernel(
    const float* __restrict__ xin, const f16* __restrict__ msgf,
    const int* __restrict__ rs, const f16* __restrict__ Rp,
    const float* __restrict__ bias, float* __restrict__ out, int do_relu) {
  __shared__ f16 Xs[NBL][XST];
  __shared__ float Sls[NBL][D];
  int t = threadIdx.x;
  int nb = blockIdx.x * NBL;

  {
    int r = t >> 2, q = t & 3;     // 4 threads per node row
    const float4* src = (const float4*)(xin + (size_t)(nb + r) * D + q * 32);
    f16* dst = &Xs[r][q * 32];
#pragma unroll
    for (int c = 0; c < 8; c++) {
      float4 v = src[c];
      f16x4 h4 = {(f16)v.x, (f16)v.y, (f16)v.z, (f16)v.w};
      *(f16x4*)(dst + c * 4) = h4;
    }
  }
  __syncthreads();

  // segment mean over contiguous sorted msg rows
  {
    int o = t & 127, g = t >> 7;
    for (int q = g * 32; q < g * 32 + 32; q++) {
      int n = nb + q;
      int a = rs[n], b = rs[n + 1];
      float s = 0.f;
      for (int r = a; r < b; r++) s += (float)msgf[(size_t)r * D + o];
      Sls[q][o] = s / (float)max(b - a, 1);
    }
  }
  __syncthreads();

  // x@root via MFMA, K=128 (4 slabs)
  int L = t & 63, w = t >> 6;
  int quad = L >> 4, lm = L & 15;
  int n0 = w * 32;
  f32x4 acc[4][2];
#pragma unroll
  for (int mt = 0; mt < 4; mt++)
#pragma unroll
    for (int nt = 0; nt < 2; nt++)
      acc[mt][nt] = (f32x4){0.f, 0.f, 0.f, 0.f};
#pragma unroll
  for (int s4 = 0; s4 < 4; s4++) {
    const f16* b2l = Rp + ((size_t)s4 * D + n0 + lm) * KH + quad * 8;
    f16x8 b0 = *(const f16x8*)b2l;
    f16x8 b1 = *(const f16x8*)(b2l + 16 * KH);
#pragma unroll
    for (int mt = 0; mt < 4; mt++) {
      f16x8 a = *(const f16x8*)&Xs[mt * 16 + lm][s4 * 32 + quad * 8];
      acc[mt][0] = __builtin_amdgcn_mfma_f32_16x16x32_f16(a, b0, acc[mt][0], 0, 0, 0);
      acc[mt][1] = __builtin_amdgcn_mfma_f32_16x16x32_f16(a, b1, acc[mt][1], 0, 0, 0);
    }
  }
#pragma unroll
  for (int mt = 0; mt < 4; mt++)
#pragma unroll
    for (int r = 0; r < 4; r++) {
      Sls[mt * 16 + quad * 4 + r][n0 + lm] += acc[mt][0][r];
      Sls[mt * 16 + quad * 4 + r][n0 + 16 + lm] += acc[mt][1][r];
    }
  __syncthreads();

  {
    int o = t & 127, g = t >> 7;
    float bo = bias[o];
    for (int q = g * 32; q < g * 32 + 32; q++) {
      float v = bo + Sls[q][o];
      out[(size_t)(nb + q) * D + o] = do_relu ? fmaxf(v, 0.0f) : v;
    }
  }
}

extern "C" void kernel_launch(void* const* d_in, const int* in_sizes, int n_in,
                              void* d_out, int out_size, void* d_ws, size_t ws_size,
                              hipStream_t stream) {
  const float* x      = (const float*)d_in[0];
  const int*   ei     = (const int*)d_in[1];
  const float* ea     = (const float*)d_in[2];
  const float* w1_l1  = (const float*)d_in[3];
  const float* b1_l1  = (const float*)d_in[4];
  const float* w1_l2  = (const float*)d_in[5];
  const float* b1_l2  = (const float*)d_in[6];
  const float* w1_rt  = (const float*)d_in[7];
  const float* b1     = (const float*)d_in[8];
  const float* w2_l1  = (const float*)d_in[9];
  const float* b2_l1  = (const float*)d_in[10];
  const float* w2_l2  = (const float*)d_in[11];
  const float* b2_l2  = (const float*)d_in[12];
  const float* w2_rt  = (const float*)d_in[13];
  const float* b2     = (const float*)d_in[14];
  float* out = (float*)d_out;

  const size_t BPSZ = (size_t)D * D * KH + (size_t)D * D;
  f16* h1f = (f16*)d_ws;                                   // E*32 f16
  f16* h2f = h1f + (size_t)N_EDGES * KH;
  f16* Bp1 = h2f + (size_t)N_EDGES * KH;
  f16* Bp2 = Bp1 + BPSZ;
  f16* Rp1 = Bp2 + BPSZ;                                   // D*D f16
  f16* Rp2 = Rp1 + (size_t)D * D;
  int* deg  = (int*)(Rp2 + (size_t)D * D);
  int* rs   = deg + N_NODES;
  int* fill = rs + N_NODES + 128;
  int* perm = fill + N_NODES;
  int* srcs = perm + N_EDGES;
  f16* msgf = (f16*)(srcs + N_EDGES);                      // E*D f16 (8.4 MB)

  hipMemsetAsync(deg, 0, N_NODES * sizeof(int), stream);
  deg_count_kernel<<<N_EDGES / 256, 256, 0, stream>>>(ei, deg);
  scan_kernel<<<1, 1024, 0, stream>>>(deg, rs, fill);
  scatter_kernel<<<N_EDGES / 256, 256, 0, stream>>>(ei, fill, perm, srcs);
  pack_all_kernel<<<dim3(D * D / 256, 6), 256, 0, stream>>>(
      w1_l2, w2_l2, b1_l2, b2_l2, w1_rt, w2_rt, Bp1, Bp2, Rp1, Rp2);
  edge_mlp_kernel<<<dim3(N_EDGES / 256, 2), 256, 0, stream>>>(
      ea, perm, w1_l1, b1_l1, w2_l1, b2_l1, h1f, h2f);

  // layer 1
  msg_mfma_kernel<<<N_EDGES / BM, 256, 0, stream>>>(x, h1f, Bp1, srcs, msgf);
  node_update_kernel<<<N_NODES / NBL, 256, 0, stream>>>(x, msgf, rs, Rp1, b1, out, 1);
  // layer 2
  msg_mfma_kernel<<<N_EDGES / BM, 256, 0, stream>>>(out, h2f, Bp2, srcs, msgf);
  node_update_kernel<<<N_NODES / NBL, 256, 0, stream>>>(out, msgf, rs, Rp2, b2, out, 1);
  // layer 3
  msg_mfma_kernel<<<N_EDGES / BM, 256, 0, stream>>>(out, h2f, Bp2, srcs, msgf);
  node_update_kernel<<<N_NODES / NBL, 256, 0, stream>>>(out, msgf, rs, Rp2, b2, out, 0);
}

// Round 5
// 359.889 us; speedup vs baseline: 1.1546x; 1.1546x over previous
//
#include <hip/hip_runtime.h>

#define N_NODES 16384
#define N_EDGES 32768
#define D 128
#define EDGE_DIM 10
#define KH 32          // edge-hidden dim
#define BM 128         // edges per msg block
#define XST 136        // padded LDS row stride (f16)
#define NBL 32         // nodes per node_update block

typedef _Float16 f16;
typedef _Float16 f16x4 __attribute__((ext_vector_type(4)));
typedef _Float16 f16x8 __attribute__((ext_vector_type(8)));
typedef float f32x4 __attribute__((ext_vector_type(4)));

// ---- CSR build ----
__global__ __launch_bounds__(256) void deg_count_kernel(
    const int* __restrict__ ei, int* __restrict__ deg) {
  int e = blockIdx.x * blockDim.x + threadIdx.x;
  if (e < N_EDGES) atomicAdd(&deg[ei[N_EDGES + e]], 1);
}

__global__ __launch_bounds__(1024) void scan_kernel(
    const int* __restrict__ deg, int* __restrict__ rs, int* __restrict__ fill) {
  __shared__ int part[1024];
  int t = threadIdx.x;
  int base = t * 16;
  int loc[16], s = 0;
#pragma unroll
  for (int j = 0; j < 16; j++) { loc[j] = deg[base + j]; s += loc[j]; }
  part[t] = s;
  __syncthreads();
  for (int off = 1; off < 1024; off <<= 1) {
    int add = (t >= off) ? part[t - off] : 0;
    __syncthreads();
    part[t] += add;
    __syncthreads();
  }
  int run = t ? part[t - 1] : 0;
#pragma unroll
  for (int j = 0; j < 16; j++) {
    rs[base + j] = run; fill[base + j] = run; run += loc[j];
  }
  if (t == 1023) rs[N_NODES] = run;
}

__global__ __launch_bounds__(256) void scatter_kernel(
    const int* __restrict__ ei, int* __restrict__ fill,
    int* __restrict__ perm, int* __restrict__ srcs) {
  int e = blockIdx.x * blockDim.x + threadIdx.x;
  if (e < N_EDGES) {
    int pos = atomicAdd(&fill[ei[N_EDGES + e]], 1);
    perm[pos] = e;
    srcs[pos] = ei[e];
  }
}

// edge MLP in dst-sorted order; blockIdx.y selects layer weights
__global__ __launch_bounds__(256) void edge_mlp_kernel(
    const float* __restrict__ ea, const int* __restrict__ perm,
    const float* __restrict__ w1l1, const float* __restrict__ b1l1,
    const float* __restrict__ w2l1, const float* __restrict__ b2l1,
    f16* __restrict__ h1, f16* __restrict__ h2) {
  int p = blockIdx.x * blockDim.x + threadIdx.x;
  const float* l1w = blockIdx.y ? w2l1 : w1l1;
  const float* l1b = blockIdx.y ? b2l1 : b1l1;
  f16* h = blockIdx.y ? h2 : h1;
  int e = perm[p];
  float a[EDGE_DIM];
#pragma unroll
  for (int d = 0; d < EDGE_DIM; d++) a[d] = ea[e * EDGE_DIM + d];
  f16 hv[KH];
#pragma unroll
  for (int k = 0; k < KH; k++) {
    float acc = l1b[k];
#pragma unroll
    for (int d = 0; d < EDGE_DIM; d++) acc += a[d] * l1w[d * KH + k];
    hv[k] = (f16)fmaxf(acc, 0.0f);
  }
  f16x8* dst = (f16x8*)(h + (size_t)p * KH);
#pragma unroll
  for (int c = 0; c < 4; c++) dst[c] = *(f16x8*)&hv[c * 8];
}

// 6 pack jobs (blockIdx.y): l2w -> Bp[i*128+o][k]; l2b/root -> K=128 slab layout
__global__ __launch_bounds__(256) void pack_all_kernel(
    const float* __restrict__ w1l2, const float* __restrict__ w2l2,
    const float* __restrict__ b1l2, const float* __restrict__ b2l2,
    const float* __restrict__ rt1, const float* __restrict__ rt2,
    f16* __restrict__ Bp1, f16* __restrict__ Bp2,
    f16* __restrict__ Rp1, f16* __restrict__ Rp2) {
  int y = blockIdx.y;
  int t = blockIdx.x * 256 + threadIdx.x;
  if (y < 2) {
    const float* l2w = y ? w2l2 : w1l2;
    f16* Bp = y ? Bp2 : Bp1;
    f16 tmp[KH];
#pragma unroll
    for (int k = 0; k < KH; k++) tmp[k] = (f16)l2w[(size_t)k * (D * D) + t];
    f16x8* dst = (f16x8*)(Bp + (size_t)t * KH);
#pragma unroll
    for (int c = 0; c < 4; c++) dst[c] = *(f16x8*)&tmp[c * 8];
  } else {
    const float* src = (y == 2) ? b1l2 : (y == 3) ? b2l2 : (y == 4) ? rt1 : rt2;
    f16* dst = (y == 2) ? (Bp1 + (size_t)D * D * KH)
             : (y == 3) ? (Bp2 + (size_t)D * D * KH)
             : (y == 4) ? Rp1 : Rp2;
    int i = t >> 7, o = t & 127;
    dst[((size_t)(i >> 5) * D + o) * KH + (i & 31)] = (f16)src[t];
  }
}

// msg GEMM: BM=128 edges/block, mt=8 m-tiles per wave, nt=2 n-tiles.
// Per b-fragment pair: 16 MFMAs (~256 cyc) -> intra-wave load hiding.
__global__ __launch_bounds__(256, 2) void msg_mfma_kernel(
    const float* __restrict__ xin, const f16* __restrict__ hf,
    const f16* __restrict__ Bp, const int* __restrict__ srcs,
    f16* __restrict__ msgf) {
  __shared__ f16 Xs[BM][XST];   // 34.8 KB
  __shared__ f16 Hs[BM][KH];    // 8 KB
  int t = threadIdx.x;
  int e0 = blockIdx.x * BM;

  ((f16x8*)Hs)[t] = ((const f16x8*)(hf + (size_t)e0 * KH))[t];
  ((f16x8*)Hs)[t + 256] = ((const f16x8*)(hf + (size_t)e0 * KH))[t + 256];
  {
    int r = t >> 1, q = t & 1;     // 2 threads per edge row
    int s = srcs[e0 + r];
    const float4* src = (const float4*)(xin + (size_t)s * D + q * 64);
    f16* dst = &Xs[r][q * 64];
#pragma unroll
    for (int c = 0; c < 16; c++) {
      float4 v = src[c];
      f16x4 h4 = {(f16)v.x, (f16)v.y, (f16)v.z, (f16)v.w};
      *(f16x4*)(dst + c * 4) = h4;
    }
  }
  __syncthreads();

  int L = t & 63, w = t >> 6;
  int quad = L >> 4, lm = L & 15;
  int n0 = w * 32;

  f16x8 hreg[8];
#pragma unroll
  for (int mt = 0; mt < 8; mt++)
    hreg[mt] = *(const f16x8*)&Hs[mt * 16 + lm][quad * 8];

  const f16* bl = Bp + (size_t)(n0 + lm) * KH + quad * 8;

  f32x4 acc[8][2];
#pragma unroll
  for (int mt = 0; mt < 8; mt++)
#pragma unroll
    for (int nt = 0; nt < 2; nt++)
      acc[mt][nt] = (f32x4){0.f, 0.f, 0.f, 0.f};

  for (int ig = 0; ig < D; ig += 8) {
    f16x8 xv[8];
#pragma unroll
    for (int mt = 0; mt < 8; mt++)
      xv[mt] = *(const f16x8*)&Xs[mt * 16 + lm][ig];
#pragma unroll
    for (int jj = 0; jj < 8; jj++) {
      const f16* bi = bl + (size_t)(ig + jj) * (D * KH);
      f16x8 b0 = *(const f16x8*)bi;
      f16x8 b1 = *(const f16x8*)(bi + 16 * KH);
#pragma unroll
      for (int mt = 0; mt < 8; mt++) {
        f16 xs = xv[mt][jj];
        f16x8 xb = {xs, xs, xs, xs, xs, xs, xs, xs};
        f16x8 a = hreg[mt] * xb;
        acc[mt][0] = __builtin_amdgcn_mfma_f32_16x16x32_f16(a, b0, acc[mt][0], 0, 0, 0);
        acc[mt][1] = __builtin_amdgcn_mfma_f32_16x16x32_f16(a, b1, acc[mt][1], 0, 0, 0);
      }
    }
  }

  // l2b fold: K=128 GEMM with A = x fragments
  {
    const f16* bb = Bp + (size_t)D * D * KH;
#pragma unroll
    for (int ig2 = 0; ig2 < 4; ig2++) {
      const f16* b2l = bb + ((size_t)ig2 * D + n0 + lm) * KH + quad * 8;
      f16x8 b0 = *(const f16x8*)b2l;
      f16x8 b1 = *(const f16x8*)(b2l + 16 * KH);
#pragma unroll
      for (int mt = 0; mt < 8; mt++) {
        f16x8 a = *(const f16x8*)&Xs[mt * 16 + lm][ig2 * 32 + quad * 8];
        acc[mt][0] = __builtin_amdgcn_mfma_f32_16x16x32_f16(a, b0, acc[mt][0], 0, 0, 0);
        acc[mt][1] = __builtin_amdgcn_mfma_f32_16x16x32_f16(a, b1, acc[mt][1], 0, 0, 0);
      }
    }
  }

  // C/D: col = lane&15 (+nt*16), row = quad*4 + reg
#pragma unroll
  for (int mt = 0; mt < 8; mt++)
#pragma unroll
    for (int r = 0; r < 4; r++) {
      f16* mg = msgf + (size_t)(e0 + mt * 16 + quad * 4 + r) * D + n0 + lm;
      mg[0] = (f16)acc[mt][0][r];
      mg[16] = (f16)acc[mt][1][r];
    }
}

// node update: out = (relu?) bias + segmean(msgf) + x@root (f16 MFMA)
__global__ __launch_bounds__(256) void node_update_kernel(
    const float* __restrict__ xin, const f16* __restrict__ msgf,
    const int* __restrict__ rs, const f16* __restrict__ Rp,
    const float* __restrict__ bias, float* __restrict__ out, int do_relu) {
  __shared__ f16 Xs[NBL][XST];   // 8.7 KB
  __shared__ float Sls[NBL][D];  // 16.4 KB
  int t = threadIdx.x;
  int nb = blockIdx.x * NBL;

  {
    int r = t >> 3, q = t & 7;   // 8 threads per node row
    const float4* src = (const float4*)(xin + (size_t)(nb + r) * D + q * 16);
    f16* dst = &Xs[r][q * 16];
#pragma unroll
    for (int c = 0; c < 4; c++) {
      float4 v = src[c];
      f16x4 h4 = {(f16)v.x, (f16)v.y, (f16)v.z, (f16)v.w};
      *(f16x4*)(dst + c * 4) = h4;
    }
  }
  __syncthreads();

  // segment mean over contiguous sorted msg rows
  {
    int o = t & 127, g = t >> 7;
    for (int q = g * 16; q < g * 16 + 16; q++) {
      int n = nb + q;
      int a = rs[n], b = rs[n + 1];
      float s = 0.f;
      for (int r = a; r < b; r++) s += (float)msgf[(size_t)r * D + o];
      Sls[q][o] = s / (float)max(b - a, 1);
    }
  }
  __syncthreads();

  // x@root via MFMA, K=128 (4 slabs), mt=2
  int L = t & 63, w = t >> 6;
  int quad = L >> 4, lm = L & 15;
  int n0 = w * 32;
  f32x4 acc[2][2];
#pragma unroll
  for (int mt = 0; mt < 2; mt++)
#pragma unroll
    for (int nt = 0; nt < 2; nt++)
      acc[mt][nt] = (f32x4){0.f, 0.f, 0.f, 0.f};
#pragma unroll
  for (int s4 = 0; s4 < 4; s4++) {
    const f16* b2l = Rp + ((size_t)s4 * D + n0 + lm) * KH + quad * 8;
    f16x8 b0 = *(const f16x8*)b2l;
    f16x8 b1 = *(const f16x8*)(b2l + 16 * KH);
#pragma unroll
    for (int mt = 0; mt < 2; mt++) {
      f16x8 a = *(const f16x8*)&Xs[mt * 16 + lm][s4 * 32 + quad * 8];
      acc[mt][0] = __builtin_amdgcn_mfma_f32_16x16x32_f16(a, b0, acc[mt][0], 0, 0, 0);
      acc[mt][1] = __builtin_amdgcn_mfma_f32_16x16x32_f16(a, b1, acc[mt][1], 0, 0, 0);
    }
  }
#pragma unroll
  for (int mt = 0; mt < 2; mt++)
#pragma unroll
    for (int r = 0; r < 4; r++) {
      Sls[mt * 16 + quad * 4 + r][n0 + lm] += acc[mt][0][r];
      Sls[mt * 16 + quad * 4 + r][n0 + 16 + lm] += acc[mt][1][r];
    }
  __syncthreads();

  {
    int o = t & 127, g = t >> 7;
    float bo = bias[o];
    for (int q = g * 16; q < g * 16 + 16; q++) {
      float v = bo + Sls[q][o];
      out[(size_t)(nb + q) * D + o] = do_relu ? fmaxf(v, 0.0f) : v;
    }
  }
}

extern "C" void kernel_launch(void* const* d_in, const int* in_sizes, int n_in,
                              void* d_out, int out_size, void* d_ws, size_t ws_size,
                              hipStream_t stream) {
  const float* x      = (const float*)d_in[0];
  const int*   ei     = (const int*)d_in[1];
  const float* ea     = (const float*)d_in[2];
  const float* w1_l1  = (const float*)d_in[3];
  const float* b1_l1  = (const float*)d_in[4];
  const float* w1_l2  = (const float*)d_in[5];
  const float* b1_l2  = (const float*)d_in[6];
  const float* w1_rt  = (const float*)d_in[7];
  const float* b1     = (const float*)d_in[8];
  const float* w2_l1  = (const float*)d_in[9];
  const float* b2_l1  = (const float*)d_in[10];
  const float* w2_l2  = (const float*)d_in[11];
  const float* b2_l2  = (const float*)d_in[12];
  const float* w2_rt  = (const float*)d_in[13];
  const float* b2     = (const float*)d_in[14];
  float* out = (float*)d_out;

  const size_t BPSZ = (size_t)D * D * KH + (size_t)D * D;
  f16* h1f = (f16*)d_ws;
  f16* h2f = h1f + (size_t)N_EDGES * KH;
  f16* Bp1 = h2f + (size_t)N_EDGES * KH;
  f16* Bp2 = Bp1 + BPSZ;
  f16* Rp1 = Bp2 + BPSZ;
  f16* Rp2 = Rp1 + (size_t)D * D;
  int* deg  = (int*)(Rp2 + (size_t)D * D);
  int* rs   = deg + N_NODES;
  int* fill = rs + N_NODES + 128;
  int* perm = fill + N_NODES;
  int* srcs = perm + N_EDGES;
  f16* msgf = (f16*)(srcs + N_EDGES);

  hipMemsetAsync(deg, 0, N_NODES * sizeof(int), stream);
  deg_count_kernel<<<N_EDGES / 256, 256, 0, stream>>>(ei, deg);
  scan_kernel<<<1, 1024, 0, stream>>>(deg, rs, fill);
  scatter_kernel<<<N_EDGES / 256, 256, 0, stream>>>(ei, fill, perm, srcs);
  pack_all_kernel<<<dim3(D * D / 256, 6), 256, 0, stream>>>(
      w1_l2, w2_l2, b1_l2, b2_l2, w1_rt, w2_rt, Bp1, Bp2, Rp1, Rp2);
  edge_mlp_kernel<<<dim3(N_EDGES / 256, 2), 256, 0, stream>>>(
      ea, perm, w1_l1, b1_l1, w2_l1, b2_l1, h1f, h2f);

  // layer 1
  msg_mfma_kernel<<<N_EDGES / BM, 256, 0, stream>>>(x, h1f, Bp1, srcs, msgf);
  node_update_kernel<<<N_NODES / NBL, 256, 0, stream>>>(x, msgf, rs, Rp1, b1, out, 1);
  // layer 2
  msg_mfma_kernel<<<N_EDGES / BM, 256, 0, stream>>>(out, h2f, Bp2, srcs, msgf);
  node_update_kernel<<<N_NODES / NBL, 256, 0, stream>>>(out, msgf, rs, Rp2, b2, out, 1);
  // layer 3
  msg_mfma_kernel<<<N_EDGES / BM, 256, 0, stream>>>(out, h2f, Bp2, srcs, msgf);
  node_update_kernel<<<N_NODES / NBL, 256, 0, stream>>>(out, msgf, rs, Rp2, b2, out, 0);
}

// Round 6
// 244.085 us; speedup vs baseline: 1.7024x; 1.4744x over previous
//
#include <hip/hip_runtime.h>

#define N_NODES 16384
#define N_EDGES 32768
#define D 128
#define EDGE_DIM 10
#define KH 32          // edge-hidden dim
#define BM 128         // edges per msg block
#define XST 136        // padded LDS row stride (f16)
#define NBL 32         // nodes per node_update block

typedef _Float16 f16;
typedef _Float16 f16x4 __attribute__((ext_vector_type(4)));
typedef _Float16 f16x8 __attribute__((ext_vector_type(8)));
typedef float f32x4 __attribute__((ext_vector_type(4)));

// ---- CSR build ----
__global__ __launch_bounds__(256) void deg_count_kernel(
    const int* __restrict__ ei, int* __restrict__ deg) {
  int e = blockIdx.x * blockDim.x + threadIdx.x;
  if (e < N_EDGES) atomicAdd(&deg[ei[N_EDGES + e]], 1);
}

__global__ __launch_bounds__(1024) void scan_kernel(
    const int* __restrict__ deg, int* __restrict__ rs, int* __restrict__ fill) {
  __shared__ int part[1024];
  int t = threadIdx.x;
  int base = t * 16;
  int loc[16], s = 0;
#pragma unroll
  for (int j = 0; j < 16; j++) { loc[j] = deg[base + j]; s += loc[j]; }
  part[t] = s;
  __syncthreads();
  for (int off = 1; off < 1024; off <<= 1) {
    int add = (t >= off) ? part[t - off] : 0;
    __syncthreads();
    part[t] += add;
    __syncthreads();
  }
  int run = t ? part[t - 1] : 0;
#pragma unroll
  for (int j = 0; j < 16; j++) {
    rs[base + j] = run; fill[base + j] = run; run += loc[j];
  }
  if (t == 1023) rs[N_NODES] = run;
}

__global__ __launch_bounds__(256) void scatter_kernel(
    const int* __restrict__ ei, int* __restrict__ fill,
    int* __restrict__ perm, int* __restrict__ srcs) {
  int e = blockIdx.x * blockDim.x + threadIdx.x;
  if (e < N_EDGES) {
    int pos = atomicAdd(&fill[ei[N_EDGES + e]], 1);
    perm[pos] = e;
    srcs[pos] = ei[e];
  }
}

// edge MLP in dst-sorted order; blockIdx.y selects layer weights
__global__ __launch_bounds__(256) void edge_mlp_kernel(
    const float* __restrict__ ea, const int* __restrict__ perm,
    const float* __restrict__ w1l1, const float* __restrict__ b1l1,
    const float* __restrict__ w2l1, const float* __restrict__ b2l1,
    f16* __restrict__ h1, f16* __restrict__ h2) {
  int p = blockIdx.x * blockDim.x + threadIdx.x;
  const float* l1w = blockIdx.y ? w2l1 : w1l1;
  const float* l1b = blockIdx.y ? b2l1 : b1l1;
  f16* h = blockIdx.y ? h2 : h1;
  int e = perm[p];
  float a[EDGE_DIM];
#pragma unroll
  for (int d = 0; d < EDGE_DIM; d++) a[d] = ea[e * EDGE_DIM + d];
  f16 hv[KH];
#pragma unroll
  for (int k = 0; k < KH; k++) {
    float acc = l1b[k];
#pragma unroll
    for (int d = 0; d < EDGE_DIM; d++) acc += a[d] * l1w[d * KH + k];
    hv[k] = (f16)fmaxf(acc, 0.0f);
  }
  f16x8* dst = (f16x8*)(h + (size_t)p * KH);
#pragma unroll
  for (int c = 0; c < 4; c++) dst[c] = *(f16x8*)&hv[c * 8];
}

// 6 pack jobs (blockIdx.y): l2w -> Bp[i*128+o][k]; l2b/root -> K=128 slab layout
__global__ __launch_bounds__(256) void pack_all_kernel(
    const float* __restrict__ w1l2, const float* __restrict__ w2l2,
    const float* __restrict__ b1l2, const float* __restrict__ b2l2,
    const float* __restrict__ rt1, const float* __restrict__ rt2,
    f16* __restrict__ Bp1, f16* __restrict__ Bp2,
    f16* __restrict__ Rp1, f16* __restrict__ Rp2) {
  int y = blockIdx.y;
  int t = blockIdx.x * 256 + threadIdx.x;
  if (y < 2) {
    const float* l2w = y ? w2l2 : w1l2;
    f16* Bp = y ? Bp2 : Bp1;
    f16 tmp[KH];
#pragma unroll
    for (int k = 0; k < KH; k++) tmp[k] = (f16)l2w[(size_t)k * (D * D) + t];
    f16x8* dst = (f16x8*)(Bp + (size_t)t * KH);
#pragma unroll
    for (int c = 0; c < 4; c++) dst[c] = *(f16x8*)&tmp[c * 8];
  } else {
    const float* src = (y == 2) ? b1l2 : (y == 3) ? b2l2 : (y == 4) ? rt1 : rt2;
    f16* dst = (y == 2) ? (Bp1 + (size_t)D * D * KH)
             : (y == 3) ? (Bp2 + (size_t)D * D * KH)
             : (y == 4) ? Rp1 : Rp2;
    int i = t >> 7, o = t & 127;
    dst[((size_t)(i >> 5) * D + o) * KH + (i & 31)] = (f16)src[t];
  }
}

// msg GEMM, explicit register double-buffer pipeline over B (i-slabs of 8).
// Bias fold = i-group at 128 (same address stream), computed in the tail with
// A = raw x fragments. (256,1): full VGPR budget, 1 block/CU by design.
__global__ __launch_bounds__(256, 1) void msg_mfma_kernel(
    const float* __restrict__ xin, const f16* __restrict__ hf,
    const f16* __restrict__ Bp, const int* __restrict__ srcs,
    f16* __restrict__ msgf) {
  __shared__ f16 Xs[BM][XST];   // 34.8 KB
  __shared__ f16 Hs[BM][KH];    // 8 KB
  int t = threadIdx.x;
  int e0 = blockIdx.x * BM;

  ((f16x8*)Hs)[t] = ((const f16x8*)(hf + (size_t)e0 * KH))[t];
  ((f16x8*)Hs)[t + 256] = ((const f16x8*)(hf + (size_t)e0 * KH))[t + 256];
  {
    int r = t >> 1, q = t & 1;     // 2 threads per edge row
    int s = srcs[e0 + r];
    const float4* src = (const float4*)(xin + (size_t)s * D + q * 64);
    f16* dst = &Xs[r][q * 64];
#pragma unroll
    for (int c = 0; c < 16; c++) {
      float4 v = src[c];
      f16x4 h4 = {(f16)v.x, (f16)v.y, (f16)v.z, (f16)v.w};
      *(f16x4*)(dst + c * 4) = h4;
    }
  }

  int L = t & 63, w = t >> 6;
  int quad = L >> 4, lm = L & 15;
  int n0 = w * 32;

  const f16* bl = Bp + (size_t)(n0 + lm) * KH + quad * 8;
  const size_t istr = (size_t)D * KH;    // f16 stride per i

  f32x4 acc[8][2];
#pragma unroll
  for (int mt = 0; mt < 8; mt++)
#pragma unroll
    for (int nt = 0; nt < 2; nt++)
      acc[mt][nt] = (f32x4){0.f, 0.f, 0.f, 0.f};

  f16x8 bufA[8][2], bufB[8][2];

  auto loadg = [&](f16x8 (&buf)[8][2], int basei) {
#pragma unroll
    for (int jj = 0; jj < 8; jj++) {
      const f16* bi = bl + (size_t)(basei + jj) * istr;
      buf[jj][0] = *(const f16x8*)bi;
      buf[jj][1] = *(const f16x8*)(bi + 16 * KH);
    }
  };

  f16x8 hreg[8];

  auto compute = [&](f16x8 (&buf)[8][2], int ig) {
    f16x8 xv[8];
#pragma unroll
    for (int mt = 0; mt < 8; mt++)
      xv[mt] = *(const f16x8*)&Xs[mt * 16 + lm][ig];
#pragma unroll
    for (int jj = 0; jj < 8; jj++) {
#pragma unroll
      for (int mt = 0; mt < 8; mt++) {
        f16 xs = xv[mt][jj];
        f16x8 xb = {xs, xs, xs, xs, xs, xs, xs, xs};
        f16x8 a = hreg[mt] * xb;
        acc[mt][0] = __builtin_amdgcn_mfma_f32_16x16x32_f16(a, buf[jj][0], acc[mt][0], 0, 0, 0);
        acc[mt][1] = __builtin_amdgcn_mfma_f32_16x16x32_f16(a, buf[jj][1], acc[mt][1], 0, 0, 0);
      }
    }
  };

  loadg(bufA, 0);                 // overlaps the staging waits: no LDS dependence
  __syncthreads();

#pragma unroll
  for (int mt = 0; mt < 8; mt++)
    hreg[mt] = *(const f16x8*)&Hs[mt * 16 + lm][quad * 8];

#pragma unroll 1
  for (int g = 0; g < 8; g++) {
    loadg(bufB, 16 * g + 8);
    compute(bufA, 16 * g);
    loadg(bufA, 16 * g + 16);     // g=7 loads i=128..135: bias slabs (jj<4) + allocated ws slack
    compute(bufB, 16 * g + 8);
  }

  // l2b fold tail: K=128 GEMM, A = raw x fragments, B already in bufA[0..3]
#pragma unroll
  for (int ig2 = 0; ig2 < 4; ig2++) {
#pragma unroll
    for (int mt = 0; mt < 8; mt++) {
      f16x8 a = *(const f16x8*)&Xs[mt * 16 + lm][ig2 * 32 + quad * 8];
      acc[mt][0] = __builtin_amdgcn_mfma_f32_16x16x32_f16(a, bufA[ig2][0], acc[mt][0], 0, 0, 0);
      acc[mt][1] = __builtin_amdgcn_mfma_f32_16x16x32_f16(a, bufA[ig2][1], acc[mt][1], 0, 0, 0);
    }
  }

  // C/D: col = lane&15 (+nt*16), row = quad*4 + reg
#pragma unroll
  for (int mt = 0; mt < 8; mt++)
#pragma unroll
    for (int r = 0; r < 4; r++) {
      f16* mg = msgf + (size_t)(e0 + mt * 16 + quad * 4 + r) * D + n0 + lm;
      mg[0] = (f16)acc[mt][0][r];
      mg[16] = (f16)acc[mt][1][r];
    }
}

// node update: out = (relu?) bias + segmean(msgf) + x@root (f16 MFMA)
__global__ __launch_bounds__(256) void node_update_kernel(
    const float* __restrict__ xin, const f16* __restrict__ msgf,
    const int* __restrict__ rs, const f16* __restrict__ Rp,
    const float* __restrict__ bias, float* __restrict__ out, int do_relu) {
  __shared__ f16 Xs[NBL][XST];   // 8.7 KB
  __shared__ float Sls[NBL][D];  // 16.4 KB
  int t = threadIdx.x;
  int nb = blockIdx.x * NBL;

  {
    int r = t >> 3, q = t & 7;   // 8 threads per node row
    const float4* src = (const float4*)(xin + (size_t)(nb + r) * D + q * 16);
    f16* dst = &Xs[r][q * 16];
#pragma unroll
    for (int c = 0; c < 4; c++) {
      float4 v = src[c];
      f16x4 h4 = {(f16)v.x, (f16)v.y, (f16)v.z, (f16)v.w};
      *(f16x4*)(dst + c * 4) = h4;
    }
  }
  __syncthreads();

  // segment mean: 8 threads per node, 16 o's per thread, 16B vector msgf reads
  {
    int nl = t >> 3, o0 = (t & 7) * 16;
    int n = nb + nl;
    int a = rs[n], b = rs[n + 1];
    float sum[16];
#pragma unroll
    for (int j = 0; j < 16; j++) sum[j] = 0.f;
    for (int r = a; r < b; r++) {
      f16x8 v0 = *(const f16x8*)(msgf + (size_t)r * D + o0);
      f16x8 v1 = *(const f16x8*)(msgf + (size_t)r * D + o0 + 8);
#pragma unroll
      for (int j = 0; j < 8; j++) {
        sum[j] += (float)v0[j];
        sum[8 + j] += (float)v1[j];
      }
    }
    float inv = 1.0f / (float)max(b - a, 1);
#pragma unroll
    for (int j = 0; j < 16; j++) Sls[nl][o0 + j] = sum[j] * inv;
  }
  __syncthreads();

  // x@root via MFMA, K=128 (4 slabs), mt=2
  int L = t & 63, w = t >> 6;
  int quad = L >> 4, lm = L & 15;
  int n0 = w * 32;
  f32x4 acc[2][2];
#pragma unroll
  for (int mt = 0; mt < 2; mt++)
#pragma unroll
    for (int nt = 0; nt < 2; nt++)
      acc[mt][nt] = (f32x4){0.f, 0.f, 0.f, 0.f};
#pragma unroll
  for (int s4 = 0; s4 < 4; s4++) {
    const f16* b2l = Rp + ((size_t)s4 * D + n0 + lm) * KH + quad * 8;
    f16x8 b0 = *(const f16x8*)b2l;
    f16x8 b1 = *(const f16x8*)(b2l + 16 * KH);
#pragma unroll
    for (int mt = 0; mt < 2; mt++) {
      f16x8 a = *(const f16x8*)&Xs[mt * 16 + lm][s4 * 32 + quad * 8];
      acc[mt][0] = __builtin_amdgcn_mfma_f32_16x16x32_f16(a, b0, acc[mt][0], 0, 0, 0);
      acc[mt][1] = __builtin_amdgcn_mfma_f32_16x16x32_f16(a, b1, acc[mt][1], 0, 0, 0);
    }
  }
#pragma unroll
  for (int mt = 0; mt < 2; mt++)
#pragma unroll
    for (int r = 0; r < 4; r++) {
      Sls[mt * 16 + quad * 4 + r][n0 + lm] += acc[mt][0][r];
      Sls[mt * 16 + quad * 4 + r][n0 + 16 + lm] += acc[mt][1][r];
    }
  __syncthreads();

  {
    int o = t & 127, g = t >> 7;
    float bo = bias[o];
    for (int q = g * 16; q < g * 16 + 16; q++) {
      float v = bo + Sls[q][o];
      out[(size_t)(nb + q) * D + o] = do_relu ? fmaxf(v, 0.0f) : v;
    }
  }
}

extern "C" void kernel_launch(void* const* d_in, const int* in_sizes, int n_in,
                              void* d_out, int out_size, void* d_ws, size_t ws_size,
                              hipStream_t stream) {
  const float* x      = (const float*)d_in[0];
  const int*   ei     = (const int*)d_in[1];
  const float* ea     = (const float*)d_in[2];
  const float* w1_l1  = (const float*)d_in[3];
  const float* b1_l1  = (const float*)d_in[4];
  const float* w1_l2  = (const float*)d_in[5];
  const float* b1_l2  = (const float*)d_in[6];
  const float* w1_rt  = (const float*)d_in[7];
  const float* b1     = (const float*)d_in[8];
  const float* w2_l1  = (const float*)d_in[9];
  const float* b2_l1  = (const float*)d_in[10];
  const float* w2_l2  = (const float*)d_in[11];
  const float* b2_l2  = (const float*)d_in[12];
  const float* w2_rt  = (const float*)d_in[13];
  const float* b2     = (const float*)d_in[14];
  float* out = (float*)d_out;

  const size_t BPSZ = (size_t)D * D * KH + (size_t)D * D;
  f16* h1f = (f16*)d_ws;
  f16* h2f = h1f + (size_t)N_EDGES * KH;
  f16* Bp1 = h2f + (size_t)N_EDGES * KH;
  f16* Bp2 = Bp1 + BPSZ;
  f16* Rp1 = Bp2 + BPSZ;
  f16* Rp2 = Rp1 + (size_t)D * D;
  int* deg  = (int*)(Rp2 + (size_t)D * D);
  int* rs   = deg + N_NODES;
  int* fill = rs + N_NODES + 128;
  int* perm = fill + N_NODES;
  int* srcs = perm + N_EDGES;
  f16* msgf = (f16*)(srcs + N_EDGES);

  hipMemsetAsync(deg, 0, N_NODES * sizeof(int), stream);
  deg_count_kernel<<<N_EDGES / 256, 256, 0, stream>>>(ei, deg);
  scan_kernel<<<1, 1024, 0, stream>>>(deg, rs, fill);
  scatter_kernel<<<N_EDGES / 256, 256, 0, stream>>>(ei, fill, perm, srcs);
  pack_all_kernel<<<dim3(D * D / 256, 6), 256, 0, stream>>>(
      w1_l2, w2_l2, b1_l2, b2_l2, w1_rt, w2_rt, Bp1, Bp2, Rp1, Rp2);
  edge_mlp_kernel<<<dim3(N_EDGES / 256, 2), 256, 0, stream>>>(
      ea, perm, w1_l1, b1_l1, w2_l1, b2_l1, h1f, h2f);

  // layer 1
  msg_mfma_kernel<<<N_EDGES / BM, 256, 0, stream>>>(x, h1f, Bp1, srcs, msgf);
  node_update_kernel<<<N_NODES / NBL, 256, 0, stream>>>(x, msgf, rs, Rp1, b1, out, 1);
  // layer 2
  msg_mfma_kernel<<<N_EDGES / BM, 256, 0, stream>>>(out, h2f, Bp2, srcs, msgf);
  node_update_kernel<<<N_NODES / NBL, 256, 0, stream>>>(out, msgf, rs, Rp2, b2, out, 1);
  // layer 3
  msg_mfma_kernel<<<N_EDGES / BM, 256, 0, stream>>>(out, h2f, Bp2, srcs, msgf);
  node_update_kernel<<<N_NODES / NBL, 256, 0, stream>>>(out, msgf, rs, Rp2, b2, out, 0);
}